// Round 18
// baseline (239.142 us; speedup 1.0000x reference)
//
#include <hip/hip_runtime.h>

// ---------------------------------------------------------------------------
// CorrelationalDetector R18: recombination of proven-best pieces.
//  convq5_k = R12's 256-wide-tile BK=64 K-half counted-vmcnt pipeline
//  (session-best fL4 53.5us, MfmaUtil 28.8 -- 256^2 amortization is the only
//  config that beat 66us; all 128^2 variants null at 24-26%) + the three
//  fixes proven since: flat-px CQ indexing, coalesced LDS-staged epilogue
//  (WRITE 81->34MB), XCD-bijective swizzle. Frame layers run with grid
//  EXACTLY 256 (1 blk/CU, no R13 tail); crop L3/L4 are separate 32-block
//  launches of the same template (latency-bound, ~5us each).
//  Heads, L2 convg4, xcorr, BN unchanged from R15/R17.
// ---------------------------------------------------------------------------

typedef __bf16 bf16x8 __attribute__((ext_vector_type(8)));
typedef float f32x4 __attribute__((ext_vector_type(4)));
typedef unsigned int u32x4 __attribute__((ext_vector_type(4)));
typedef unsigned int u32x2 __attribute__((ext_vector_type(2)));
typedef unsigned short u16;

#define AS1 __attribute__((address_space(1)))
#define AS3 __attribute__((address_space(3)))

__device__ __forceinline__ u16 f2bf(float v) {
    unsigned u = __float_as_uint(v);
    u += 0x7fffu + ((u >> 16) & 1u);          // RNE
    return (u16)(u >> 16);
}

__device__ __forceinline__ bf16x8 ldb8(const u16* p) {
    return *(const bf16x8*)p;
}

__device__ __forceinline__ bf16x8 zerob8() {
    u32x4 z = {0u, 0u, 0u, 0u};
    bf16x8 r;
    __builtin_memcpy(&r, &z, 16);
    return r;
}

__device__ __forceinline__ void gload16(const u16* g, u16* l) {
    __builtin_amdgcn_global_load_lds((const AS1 void*)g, (AS3 void*)l, 16, 0, 0);
}

template<int N> __device__ __forceinline__ void wait_vm() {
    asm volatile("s_waitcnt vmcnt(%0)" :: "i"(N) : "memory");
}

__device__ __forceinline__ void bar_mem() {
    asm volatile("" ::: "memory");
    __builtin_amdgcn_s_barrier();
    asm volatile("" ::: "memory");
}

// XCD-bijective logical block id (requires gridDim.x % 8 == 0)
__device__ __forceinline__ int xcd_logical() {
    const int nb = (int)gridDim.x;
    return ((int)blockIdx.x & 7) * (nb >> 3) + ((int)blockIdx.x >> 3);
}

// per-side geometry
struct CP { const u16* in; u16* out; int IWp, inSS, OWsh, OWpo, outSS, npt; };
struct CQ { const u16* in; u16* out; int IWp, inSS, HWsh, OWsh, OWpo, outSS, pad_o; };

// ---- merged prep: weight pack (blocks [0,1484)) + halo zero (rest) ---------
struct HZd { unsigned long long ptr; int B, Hp, Wpx, w8, cum; };
struct HZall { HZd d[8]; int total; };

__device__ __forceinline__ void packone(const float* W, u16* Wp, int idx,
                                        int ICsh, int Kpad)
{
    const int k = idx % Kpad, oc = idx / Kpad;
    const int tap = k >> ICsh, ic = k & ((1 << ICsh) - 1);
    const float v = (tap < 9) ? W[((size_t)(oc << ICsh) + ic) * 9 + tap] : 0.f;
    Wp[idx] = f2bf(v);
}

__global__ __launch_bounds__(256)
void prep_k(HZall h,
            const float* __restrict__ W1, const float* __restrict__ W2,
            const float* __restrict__ W3, const float* __restrict__ W4,
            u16* __restrict__ Wc1, u16* __restrict__ Wp2,
            u16* __restrict__ Wp3, u16* __restrict__ Wp4)
{
    if (blockIdx.x < 1484) {
        const int i = blockIdx.x * 256 + threadIdx.x;
        if (i < 1024) {                       // Wc1: [16][64], k = ky*16+kx*4+ic
            const int k = i & 63, oc = i >> 6;
            const int ky = k >> 4, kx = (k >> 2) & 3, ic = k & 3;
            const float v = (ky < 3 && kx < 3 && ic < 3) ? W1[oc * 27 + ic * 9 + ky * 3 + kx] : 0.f;
            Wc1[i] = f2bf(v);
        } else if (i < 11264) {
            packone(W2, Wp2, i - 1024, 4, 160);
        } else if (i < 84992) {
            packone(W3, Wp3, i - 11264, 6, 576);
        } else if (i < 379904) {
            packone(W4, Wp4, i - 84992, 7, 1152);
        }
        return;
    }
    const int nblk = gridDim.x - 1484;
    for (int i = (blockIdx.x - 1484) * 256 + threadIdx.x; i < h.total; i += nblk * 256) {
        int di = 0;
        #pragma unroll
        for (int j = 1; j < 8; ++j) if (i >= h.d[j].cum) di = j;
        const HZd D = h.d[di];
        const int loc = i - D.cum;
        const int w = loc % D.w8; int t2 = loc / D.w8;
        const int bord = 2 * D.Wpx + 2 * (D.Hp - 2);
        const int pb = t2 % bord; const int b = t2 / bord;
        int oh, ow;
        if (pb < D.Wpx)            { oh = 0;        ow = pb; }
        else if (pb < 2 * D.Wpx)   { oh = D.Hp - 1; ow = pb - D.Wpx; }
        else { const int q = pb - 2 * D.Wpx; oh = 1 + (q >> 1); ow = (q & 1) ? (D.Wpx - 1) : 0; }
        ((unsigned long long*)D.ptr)[((size_t)b * D.Hp * D.Wpx + (size_t)oh * D.Wpx + ow) * D.w8 + w] = 0ull;
    }
}

// ---- L0 body ----------------------------------------------------------------
__device__ __forceinline__ void conv0_body(const float* __restrict__ in,
                                           const float* __restrict__ W,
                                           const float* __restrict__ bias,
                                           u16* __restrict__ outP,
                                           int IH, int IW, int OH, int OW, int idx)
{
    const int OW4 = OW >> 2;
    const int OWp = OW + 2, OHp = OH + 2;
    const int ow4 = idx % OW4; int t = idx / OW4;
    const int oh = t % OH;  const int b = t / OH;
    const int owb = ow4 * 4;
    float a0[4], a1[4], a2[4];
    #pragma unroll
    for (int j = 0; j < 4; ++j) { a0[j] = bias[0]; a1[j] = bias[1]; a2[j] = bias[2]; }
    const float* inb = in + (size_t)b * 3 * IH * IW;
    const int xbase = owb * 2 - 1;
    #pragma unroll
    for (int ic = 0; ic < 3; ++ic) {
        const float* ip = inb + (size_t)ic * IH * IW;
        #pragma unroll
        for (int ky = 0; ky < 3; ++ky) {
            const int y = oh * 2 - 1 + ky;
            if ((unsigned)y >= (unsigned)IH) continue;
            const float* rp = ip + (size_t)y * IW;
            float xr[9];
            #pragma unroll
            for (int i2 = 0; i2 < 9; ++i2) {
                const int x = xbase + i2;
                xr[i2] = ((unsigned)x < (unsigned)IW) ? rp[x] : 0.f;
            }
            #pragma unroll
            for (int kx = 0; kx < 3; ++kx) {
                const float w0 = W[0 * 27 + ic * 9 + ky * 3 + kx];
                const float w1 = W[1 * 27 + ic * 9 + ky * 3 + kx];
                const float w2 = W[2 * 27 + ic * 9 + ky * 3 + kx];
                #pragma unroll
                for (int j = 0; j < 4; ++j) {
                    const float xv = xr[2 * j + kx];
                    a0[j] += xv * w0; a1[j] += xv * w1; a2[j] += xv * w2;
                }
            }
        }
    }
    u16* op = outP + (((size_t)b * OHp + oh + 1) * OWp + owb + 1) * 4;
    #pragma unroll
    for (int j = 0; j < 4; ++j) {
        u32x2 pk;
        pk[0] = (unsigned)f2bf(fmaxf(a0[j], 0.f)) | ((unsigned)f2bf(fmaxf(a1[j], 0.f)) << 16);
        pk[1] = (unsigned)f2bf(fmaxf(a2[j], 0.f));
        *(u32x2*)(op + j * 4) = pk;
    }
}

__global__ __launch_bounds__(256)
void conv0m_k(const float* __restrict__ crop, const float* __restrict__ frame,
              const float* __restrict__ W, const float* __restrict__ bias,
              u16* __restrict__ c0b, u16* __restrict__ f0b)
{
    if (blockIdx.x < 64)
        conv0_body(crop, W, bias, c0b, 64, 64, 32, 32, blockIdx.x * 256 + threadIdx.x);
    else
        conv0_body(frame, W, bias, f0b, 256, 256, 128, 128, (blockIdx.x - 64) * 256 + threadIdx.x);
}

// ---- L1 body: MFMA GEMM M=16 oc, K=64 --------------------------------------
__device__ __forceinline__ void conv1g_body(const u16* __restrict__ inP,
                                            const u16* __restrict__ Wc1,
                                            const float* __restrict__ bias,
                                            u16* __restrict__ outP,
                                            int IWp, int inSS, int OWp, int outSS,
                                            int OWsh, int HWsh, int w, int lane)
{
    const int lr = lane & 15, lg = lane >> 4;
    const int pxb = w * 64;
    const int OW = 1 << OWsh;

    const bf16x8 av0 = ldb8(Wc1 + lr * 64 + lg * 8);
    const bf16x8 av1 = ldb8(Wc1 + lr * 64 + 32 + lg * 8);
    const int ky0 = lg >> 1, kxb = (lg & 1) * 2;
    const int ky1 = 2 + (lg >> 1);

    f32x4 acc[4] = {};
    #pragma unroll
    for (int n = 0; n < 4; ++n) {
        const int px = pxb + n * 16 + lr;
        const int b = px >> HWsh;
        const int rem = px & ((1 << HWsh) - 1);
        const int oh = rem >> OWsh, ow = rem & (OW - 1);
        const u16* ib = inP + (size_t)b * inSS + (((size_t)(oh * 2)) * IWp + ow * 2) * 4;
        const bf16x8 bv0 = ldb8(ib + ((size_t)ky0 * IWp + kxb) * 4);
        acc[n] = __builtin_amdgcn_mfma_f32_16x16x32_bf16(av0, bv0, acc[n], 0, 0, 0);
        const bf16x8 bv1 = ldb8(ib + ((size_t)ky1 * IWp + kxb) * 4);
        acc[n] = __builtin_amdgcn_mfma_f32_16x16x32_bf16(av1, bv1, acc[n], 0, 0, 0);
    }

    const float b0 = bias[lg * 4], b1 = bias[lg * 4 + 1],
                b2 = bias[lg * 4 + 2], b3 = bias[lg * 4 + 3];
    #pragma unroll
    for (int n = 0; n < 4; ++n) {
        const int px = pxb + n * 16 + lr;
        const int b = px >> HWsh;
        const int rem = px & ((1 << HWsh) - 1);
        const int oh = rem >> OWsh, ow = rem & (OW - 1);
        const f32x4 a = acc[n];
        u32x2 pk;
        pk[0] = (unsigned)f2bf(fmaxf(a[0] + b0, 0.f)) | ((unsigned)f2bf(fmaxf(a[1] + b1, 0.f)) << 16);
        pk[1] = (unsigned)f2bf(fmaxf(a[2] + b2, 0.f)) | ((unsigned)f2bf(fmaxf(a[3] + b3, 0.f)) << 16);
        u16* op = outP + (size_t)b * outSS + (((size_t)(oh + 1)) * OWp + (ow + 1)) * 16 + lg * 4;
        *(u32x2*)op = pk;
    }
}

__global__ __launch_bounds__(256)
void conv1m_k(const u16* __restrict__ c0b, u16* __restrict__ c1p,
              const u16* __restrict__ f0b, u16* __restrict__ f1p,
              const u16* __restrict__ Wc1, const float* __restrict__ bias)
{
    const int wv = threadIdx.x >> 6, lane = threadIdx.x & 63;
    if (blockIdx.x < 64)
        conv1g_body(c0b, Wc1, bias, c1p, 34, 4624, 18, 5184, 4, 8, blockIdx.x * 4 + wv, lane);
    else
        conv1g_body(f0b, Wc1, bias, f1p, 130, 67600, 66, 69696, 6, 12, (blockIdx.x - 64) * 4 + wv, lane);
}

// ---- convq5: R12 256-wide-tile BK=64 K-half counted-vmcnt pipeline ---------
// (8 waves 512t, wave tile (BM/NWM)x(BN/NWN), 16x16x32 MFMA) + flat-px CQ +
// coalesced LDS-staged epilogue + XCD swizzle. BM == OC (ocb = 0).
template<int BM, int BN, int NWM, int NWN, int S>
__global__ __launch_bounds__(512, 2)
void convq5_k(CQ P, const u16* __restrict__ Wp, const float* __restrict__ bias,
              int IC_sh, int nt, int Kpad, int relu)
{
    constexpr int MF = BM / (NWM * 16);
    constexpr int NF = BN / (NWN * 16);
    constexpr int AH = BM * 4 / 512;       // loads/thread per A k-half piece
    constexpr int BH = BN * 4 / 512;
    constexpr int WAIT  = 2 * AH + BH;     // R12 steady-state counted vmcnt
    constexpr int TAIL0 = AH + BH;
    constexpr int ASZ = 2 * 2 * BM * 4 * 8;   // u16 elements
    constexpr int BSZ = 2 * 2 * BN * 4 * 8;

    __shared__ __align__(16) u16 SM[ASZ + BSZ];
    u16* Ab = SM;
    u16* Bb = SM + ASZ;

    const int pt = xcd_logical();

    const int t    = threadIdx.x;
    const int lane = t & 63;
    const int lr   = lane & 15, lg = lane >> 4;
    const int wv   = t >> 6;
    const int wm   = wv / NWN, wn = wv % NWN;

    const int IC = 1 << IC_sh;
    const int OW = 1 << P.OWsh;
    const int HWm = (1 << P.HWsh) - 1;
    const int pxb = pt * BN;

    const u16* apg[2 * AH];
    #pragma unroll
    for (int h = 0; h < 2; ++h)
        #pragma unroll
        for (int i = 0; i < AH; ++i) {
            const int j = i * 512 + t;
            const int row = j >> 2, o = j & 3;
            const int oct = h * 4 + (o ^ ((row ^ (row >> 2)) & 3));
            apg[h * AH + i] = Wp + (size_t)row * Kpad + oct * 8;
        }
    const u16* bpg[2 * BH];
    #pragma unroll
    for (int h = 0; h < 2; ++h)
        #pragma unroll
        for (int i = 0; i < BH; ++i) {
            const int j = i * 512 + t;
            const int row = j >> 2, o = j & 3;
            const int oct = h * 4 + (o ^ ((row ^ (row >> 2)) & 3));
            const int px = pxb + row;
            const int b = px >> P.HWsh;
            const int rem = px & HWm;
            const int oh = rem >> P.OWsh, ow = rem & (OW - 1);
            bpg[h * BH + i] = P.in + (size_t)b * P.inSS
                            + ((size_t)(oh * S) * P.IWp + ow * S) * IC + oct * 8;
        }

    f32x4 acc[MF][NF] = {};

    auto STAGE_A = [&](int buf, int h, int kb) {
        u16* dst = Ab + (size_t)((buf * 2 + h) * BM * 4) * 8;
        #pragma unroll
        for (int i = 0; i < AH; ++i)
            gload16(apg[h * AH + i] + kb, dst + (size_t)(i * 512 + t) * 8);
    };
    auto STAGE_B = [&](int buf, int h, int kb) {
        const int tap = kb >> IC_sh;          // uniform: BK=64 <= IC
        const int ky = (tap * 11) >> 5, kx = tap - 3 * ky;
        const size_t off = ((size_t)(ky * P.IWp + kx) << IC_sh) + (kb & (IC - 1));
        u16* dst = Bb + (size_t)((buf * 2 + h) * BN * 4) * 8;
        #pragma unroll
        for (int i = 0; i < BH; ++i)
            gload16(bpg[h * BH + i] + off, dst + (size_t)(i * 512 + t) * 8);
    };

    // prologue: tile 0, FIFO order Ak0, Bk0, Ak1, Bk1
    STAGE_A(0, 0, 0); STAGE_B(0, 0, 0); STAGE_A(0, 1, 0); STAGE_B(0, 1, 0);

    for (int ks = 0; ks < nt; ++ks) {
        const int cur = ks & 1, nxt = cur ^ 1;
        const int kb1 = (ks + 1) * 64;
        const bool pf = (ks + 1 < nt);
        bf16x8 af[MF], bf_[NF];

        #pragma unroll
        for (int kk = 0; kk < 2; ++kk) {
            if (pf) STAGE_A(nxt, kk, kb1);
            if (pf)            wait_vm<WAIT>();
            else if (kk == 0)  wait_vm<TAIL0>();
            else               wait_vm<0>();
            bar_mem();                         // k-half kk of tile ks ready

            const u16* Abase = Ab + (size_t)((cur * 2 + kk) * BM * 4) * 8;
            const u16* Bbase = Bb + (size_t)((cur * 2 + kk) * BN * 4) * 8;
            #pragma unroll
            for (int n = 0; n < NF; ++n) {
                const int row = wn * (NF * 16) + n * 16 + lr;
                const int o = lg ^ ((row ^ (row >> 2)) & 3);
                bf_[n] = ldb8(Bbase + (size_t)(row * 4 + o) * 8);
            }
            #pragma unroll
            for (int m = 0; m < MF; ++m) {
                const int row = wm * (MF * 16) + m * 16 + lr;
                const int o = lg ^ ((row ^ (row >> 2)) & 3);
                af[m] = ldb8(Abase + (size_t)(row * 4 + o) * 8);
            }
            if (pf) STAGE_B(nxt, kk, kb1);

            __builtin_amdgcn_s_setprio(1);
            #pragma unroll
            for (int m = 0; m < MF; ++m)
                #pragma unroll
                for (int n = 0; n < NF; ++n)
                    acc[m][n] = __builtin_amdgcn_mfma_f32_16x16x32_bf16(af[m], bf_[n], acc[m][n], 0, 0, 0);
            __builtin_amdgcn_s_setprio(0);
        }
    }

    // ---- coalesced epilogue via LDS C-tile (BN x BM bf16) ----
    bar_mem();
    unsigned long long* SM64 = (unsigned long long*)SM;
    #pragma unroll
    for (int m = 0; m < MF; ++m) {
        const int ocl = wm * (MF * 16) + m * 16 + lg * 4;
        const float b0 = bias[ocl], b1 = bias[ocl + 1],
                    b2 = bias[ocl + 2], b3 = bias[ocl + 3];
        #pragma unroll
        for (int n = 0; n < NF; ++n) {
            const int px = wn * (NF * 16) + n * 16 + lr;
            const f32x4 a = acc[m][n];
            float v0 = a[0] + b0, v1 = a[1] + b1, v2 = a[2] + b2, v3 = a[3] + b3;
            if (relu) {
                v0 = fmaxf(v0, 0.f); v1 = fmaxf(v1, 0.f);
                v2 = fmaxf(v2, 0.f); v3 = fmaxf(v3, 0.f);
            }
            u32x2 pk;
            pk[0] = (unsigned)f2bf(v0) | ((unsigned)f2bf(v1) << 16);
            pk[1] = (unsigned)f2bf(v2) | ((unsigned)f2bf(v3) << 16);
            const int sw = ((px & 3) << 1) | ((px >> 2) & 1);
            const int u8 = (ocl >> 2) ^ (sw << 1);
            *(u32x2*)&SM64[(size_t)px * (BM / 4) + u8] = pk;
        }
    }
    bar_mem();
    constexpr int UPX16 = BM / 8;             // 16B units per px row
    constexpr int NIT = BN * UPX16 / 512;
    #pragma unroll
    for (int it = 0; it < NIT; ++it) {
        const int g = it * 512 + t;
        const int px = g / UPX16;
        const int ul = g & (UPX16 - 1);
        const int sw = ((px & 3) << 1) | ((px >> 2) & 1);
        const int phys = ul ^ sw;
        const u32x4 val = *(const u32x4*)&SM[((size_t)px * UPX16 + phys) * 8];
        const int flat = pxb + px;
        const int b = flat >> P.HWsh;
        const int rem = flat & HWm;
        const int oh = rem >> P.OWsh, ow = rem & (OW - 1);
        u16* dst = P.out + (size_t)b * P.outSS
                 + (((size_t)(oh + P.pad_o)) * P.OWpo + (ow + P.pad_o)) * BM + ul * 8;
        *(u32x4*)dst = val;
    }
}

// ---- convg4: L2 conv, 4-buffer 3-deep pipeline with COALESCED staging ------
template<int BM, int BN, int NWM, int NWN, int S>
__global__ __launch_bounds__(256, 2)
void convg4_k(CP A, CP B, int split,
              const u16* __restrict__ Wp, const float* __restrict__ bias,
              int IC_sh, int pad_o, int Kreal, int nt, int Kpad, int relu, int OCtot)
{
    constexpr int MF = BM / (NWM * 16);
    constexpr int NF = BN / (NWN * 16);
    constexpr int ASLOT = BM * 4;
    constexpr int BSLOT = BN * 4;
    constexpr int AISS = ASLOT / 256;
    constexpr int BISS = BSLOT / 256;
    constexpr int NSTG = AISS + BISS;

    __shared__ __align__(16) u16 Ab[4][ASLOT * 8];
    __shared__ __align__(16) u16 Bb[4][BSLOT * 8];

    const int lbid = xcd_logical();
    CP P; int bid;
    if (lbid < split) { P = A; bid = lbid; }
    else              { P = B; bid = lbid - split; }

    const int t    = threadIdx.x;
    const int wv   = t >> 6, lane = t & 63;
    const int lr   = lane & 15, lg = lane >> 4;
    const int wm   = wv / NWN, wn = wv % NWN;

    const int tilesPerB = (OCtot / BM) * P.npt;
    const int b  = bid / tilesPerB;
    const int r0 = bid - b * tilesPerB;
    const int mt = r0 / P.npt, pt = r0 - mt * P.npt;
    const int ocb = mt * BM, pxb = pt * BN;
    const int IC = 1 << IC_sh;
    const int OW = 1 << P.OWsh;

    const u16* __restrict__ inb = P.in + (size_t)b * P.inSS;

    const u16* agp[AISS];
    #pragma unroll
    for (int i = 0; i < AISS; ++i) {
        const int j = i * 256 + t;
        const int row = j >> 2, c = j & 3;
        const int og = c ^ ((row ^ (row >> 2)) & 3);
        agp[i] = Wp + (size_t)(ocb + row) * Kpad + og * 8;
    }
    const u16* bpx[BISS]; int bog8[BISS];
    #pragma unroll
    for (int i = 0; i < BISS; ++i) {
        const int j = i * 256 + t;
        const int row = j >> 2, c = j & 3;
        const int og = c ^ ((row ^ (row >> 2)) & 3);
        const int px = pxb + row;
        const int oh = px >> P.OWsh, ow = px & (OW - 1);
        bpx[i] = inb + ((size_t)(oh * S) * P.IWp + ow * S) * IC;
        bog8[i] = og * 8;
    }

    f32x4 acc[MF][NF] = {};

    auto STAGE = [&](int buf, int kb) {
        #pragma unroll
        for (int i = 0; i < AISS; ++i)
            gload16(agp[i] + kb, &Ab[buf][(size_t)(i * 256 + t) * 8]);
        #pragma unroll
        for (int i = 0; i < BISS; ++i) {
            const int k = kb + bog8[i];
            const int tap = k >> IC_sh;
            const int ic = k & (IC - 1);
            const int ky = (tap * 11) >> 5, kx = tap - 3 * ky;
            const u16* g = bpx[i] + ((size_t)ky * P.IWp + kx) * IC + ic;
            if (k >= Kreal) g = inb;           // A is zero there; any valid addr
            gload16(g, &Bb[buf][(size_t)(i * 256 + t) * 8]);
        }
    };

    STAGE(0, 0);
    if (1 < nt) STAGE(1, 32);
    if (2 < nt) STAGE(2, 64);

    for (int ks = 0; ks < nt; ++ks) {
        const int rem = nt - 1 - ks;
        if (rem >= 2)      wait_vm<2 * NSTG>();
        else if (rem == 1) wait_vm<NSTG>();
        else               wait_vm<0>();
        bar_mem();
        if (ks + 3 < nt) STAGE((ks + 3) & 3, (ks + 3) * 32);

        const int cur = ks & 3;
        bf16x8 af[MF], bf_[NF];
        #pragma unroll
        for (int m = 0; m < MF; ++m) {
            const int row = wm * (MF * 16) + m * 16 + lr;
            const int o = lg ^ ((row ^ (row >> 2)) & 3);
            af[m] = ldb8(&Ab[cur][(size_t)(row * 4 + o) * 8]);
        }
        #pragma unroll
        for (int n = 0; n < NF; ++n) {
            const int row = wn * (NF * 16) + n * 16 + lr;
            const int o = lg ^ ((row ^ (row >> 2)) & 3);
            bf_[n] = ldb8(&Bb[cur][(size_t)(row * 4 + o) * 8]);
        }

        __builtin_amdgcn_s_setprio(1);
        #pragma unroll
        for (int m = 0; m < MF; ++m)
            #pragma unroll
            for (int n = 0; n < NF; ++n)
                acc[m][n] = __builtin_amdgcn_mfma_f32_16x16x32_bf16(af[m], bf_[n], acc[m][n], 0, 0, 0);
        __builtin_amdgcn_s_setprio(0);
    }

    #pragma unroll
    for (int m = 0; m < MF; ++m) {
        const int oc0 = ocb + wm * (MF * 16) + m * 16 + lg * 4;
        const float b0 = bias[oc0], b1 = bias[oc0 + 1], b2 = bias[oc0 + 2], b3 = bias[oc0 + 3];
        #pragma unroll
        for (int n = 0; n < NF; ++n) {
            const int px = pxb + wn * (NF * 16) + n * 16 + lr;
            const int oh = px >> P.OWsh, ow = px & (OW - 1);
            const f32x4 a = acc[m][n];
            float v0 = a[0] + b0, v1 = a[1] + b1, v2 = a[2] + b2, v3 = a[3] + b3;
            if (relu) {
                v0 = fmaxf(v0, 0.f); v1 = fmaxf(v1, 0.f);
                v2 = fmaxf(v2, 0.f); v3 = fmaxf(v3, 0.f);
            }
            u32x2 pk;
            pk[0] = (unsigned)f2bf(v0) | ((unsigned)f2bf(v1) << 16);
            pk[1] = (unsigned)f2bf(v2) | ((unsigned)f2bf(v3) << 16);
            u16* op = P.out + (size_t)b * P.outSS +
                      (((size_t)(oh + pad_o)) * P.OWpo + (ow + pad_o)) * (size_t)OCtot + oc0;
            *(u32x2*)op = pk;
        }
    }
}

// ---- xcorr as batched MFMA GEMM --------------------------------------------
__global__ __launch_bounds__(256)
void xcmf_k(const u16* __restrict__ ffm, const u16* __restrict__ cfm,
            float* __restrict__ R)
{
    const int w    = blockIdx.x * 4 + (threadIdx.x >> 6);   // 1600 waves
    const int lane = threadIdx.x & 63;
    const int lr   = lane & 15, lg = lane >> 4;
    const int b  = w / 25;
    const int tp = w - b * 25;

    const int col0 = tp * 32 + lr;
    const int col1 = col0 + 16;
    const int y0 = col0 / 25, x0 = col0 - y0 * 25;
    const int y1 = col1 / 25, x1 = col1 - y1 * 25;

    const u16* fb = ffm + (size_t)b * 262144;
    const u16* f0 = fb + ((size_t)y0 * 32 + x0) * 256 + lg * 8;
    const u16* f1 = fb + ((size_t)y1 * 32 + x1) * 256 + lg * 8;
    const u16* ab = cfm + (size_t)b * 16384 + (size_t)lr * 2048 + lg * 8;
    const bool arow = (lr < 8);

    f32x4 acc0 = {}, acc1 = {};
    #pragma unroll 4
    for (int kb = 0; kb < 2048; kb += 32) {
        const bf16x8 av = arow ? ldb8(ab + kb) : zerob8();
        const bf16x8 bv0 = ldb8(f0 + kb);
        const bf16x8 bv1 = ldb8(f1 + kb);
        acc0 = __builtin_amdgcn_mfma_f32_16x16x32_bf16(av, bv0, acc0, 0, 0, 0);
        acc1 = __builtin_amdgcn_mfma_f32_16x16x32_bf16(av, bv1, acc1, 0, 0, 0);
    }

    if (lg < 2) {
        float* rb = R + (size_t)b * 6400;
        #pragma unroll
        for (int j = 0; j < 4; ++j) {
            const int d = lg * 4 + j;
            rb[(size_t)d * 800 + col0] = acc0[j];
            rb[(size_t)d * 800 + col1] = acc1[j];
        }
    }
}

// ---- BatchNorm (with fused diagonal-band reduce) ---------------------------
__global__ __launch_bounds__(1024)
void bn_k(const float* __restrict__ R, float* __restrict__ part,
          const float* __restrict__ gamma, const float* __restrict__ beta,
          float* __restrict__ out)
{
    const int N = 40000;
    const int tid = threadIdx.x;
    __shared__ float rs[1024], rq[1024];
    __shared__ float mean_s, inv_s;
    float s = 0.f, q = 0.f;
    for (int i = tid; i < N; i += 1024) {
        const int b = i / 625;
        const int o = i - b * 625;
        const float* rb = R + (size_t)b * 6400 + o;
        float v = 0.f;
        #pragma unroll
        for (int d = 0; d < 8; ++d) v += rb[(size_t)d * 800 + d * 25];
        part[i] = v;
        s += v; q += v * v;
    }
    rs[tid] = s; rq[tid] = q;
    __syncthreads();
    for (int off = 512; off > 0; off >>= 1) {
        if (tid < off) { rs[tid] += rs[tid + off]; rq[tid] += rq[tid + off]; }
        __syncthreads();
    }
    if (tid == 0) {
        const float m = rs[0] / (float)N;
        mean_s = m;
        inv_s = rsqrtf(rq[0] / (float)N - m * m + 1e-5f);
    }
    __syncthreads();
    const float g = gamma[0], bt = beta[0];
    for (int i = tid; i < N; i += 1024)
        out[i] = (part[i] - mean_s) * inv_s * g + bt;
}

// ---------------------------------------------------------------------------

extern "C" void kernel_launch(void* const* d_in, const int* in_sizes, int n_in,
                              void* d_out, int out_size, void* d_ws, size_t ws_size,
                              hipStream_t stream)
{
    (void)in_sizes; (void)n_in; (void)out_size; (void)ws_size;
    const float* crop  = (const float*)d_in[0];
    const float* frame = (const float*)d_in[1];
    const float* W[5]; const float* bb[5];
    for (int i = 0; i < 5; ++i) { W[i] = (const float*)d_in[2 + 2*i]; bb[i] = (const float*)d_in[3 + 2*i]; }
    const float* gamma = (const float*)d_in[12];
    const float* beta  = (const float*)d_in[13];
    float* out = (float*)d_out;

    unsigned char* ws = (unsigned char*)d_ws;
    u16*   f0b  = (u16*)(ws + 0);             // [64][130][130][4]   8,652,800 B (dead after fL1)
    u16*   f1p  = (u16*)(ws + 8652800);       // [64][66][66][16]    8,921,088 B (dead after fL2)
    u16*   f2p  = (u16*)(ws + 17573888);      // [64][66][66][64]   35,684,352 B (dead after fL3)
    u16*   f3p  = (u16*)(ws + 53258240);      // [64][34][34][128]  18,939,904 B
    u16*   ffm  = (u16*)(ws + 0);             // [64][32][32][256]  33,554,432 B (aliases dead f0b..f2p)
    u16*   c0b  = (u16*)(ws + 72198144);      // [64][34][34][4]       591,872 B
    u16*   c1p  = (u16*)(ws + 72790016);      // [64][18][18][16]      663,552 B
    u16*   c2p  = (u16*)(ws + 73453568);      // [64][18][18][64]    2,654,208 B
    u16*   c3p  = (u16*)(ws + 76107776);      // [64][10][10][128]   1,638,400 B
    u16*   cfm  = (u16*)(ws + 77746176);      // [64][8][8][256]     2,097,152 B
    u16*   Wc1  = (u16*)(ws + 79843328);      // [16][64]
    u16*   Wp2  = (u16*)(ws + 79845376);      // [64][160]
    u16*   Wp3  = (u16*)(ws + 79865856);      // [128][576]
    u16*   Wp4  = (u16*)(ws + 80013312);      // [256][1152]
    float* Rbuf = (float*)(ws + 80603136);    // [64][8][800] f32
    float* part = (float*)(ws + 82241536);    // [40000] f32

    // ---- merged prep (weight pack + halo zero), one launch ----
    HZall hz;
    const unsigned long long ptrs[8] = {(unsigned long long)c0b, (unsigned long long)c1p,
        (unsigned long long)c2p, (unsigned long long)c3p, (unsigned long long)f0b,
        (unsigned long long)f1p, (unsigned long long)f2p, (unsigned long long)f3p};
    const int Hps[8] = {34, 18, 18, 10, 130, 66, 66, 34};
    const int w8s[8] = {1, 4, 16, 32, 1, 4, 16, 32};
    int cum = 0;
    for (int i = 0; i < 8; ++i) {
        hz.d[i].ptr = ptrs[i]; hz.d[i].B = 64; hz.d[i].Hp = Hps[i];
        hz.d[i].Wpx = Hps[i]; hz.d[i].w8 = w8s[i]; hz.d[i].cum = cum;
        cum += 64 * (2 * Hps[i] + 2 * (Hps[i] - 2)) * w8s[i];
    }
    hz.total = cum;
    prep_k<<<1856, 256, 0, stream>>>(hz, W[1], W[2], W[3], W[4], Wc1, Wp2, Wp3, Wp4);

    // ---- merged heads (crop+frame): L0, L1, L2 ----
    conv0m_k<<<1088, 256, 0, stream>>>(crop, frame, W[0], bb[0], c0b, f0b);
    conv1m_k<<<1088, 256, 0, stream>>>(c0b, c1p, f0b, f1p, Wc1, bb[1]);
    {
        CP Ac = {c1p, c2p, 18,  5184, 4, 18, 20736,  1};
        CP Bf = {f1p, f2p, 66, 69696, 6, 66, 278784, 16};
        convg4_k<64,256,1,4,1><<<1088, 256, 0, stream>>>(Ac, Bf, 64, Wp2, bb[2],
            4, 1, 144, 5, 160, 1, 64);
    }

    // ---- L3/L4: frame at 256-wide tiles (grid exactly 256, 1 blk/CU),
    //      crop as separate small launches of the same template ----
    {
        //        in   out  IWp inSS    HWsh OWsh OWpo outSS  pad
        CQ F3 = {f2p, f3p, 66, 278784, 10,  5,   34,  147968, 1};
        CQ C3 = {c2p, c3p, 18,  20736,  6,  3,   10,   12800, 1};
        convq5_k<128,256,2,4,2><<<256, 512, 0, stream>>>(F3, Wp3, bb[3], 6,  9,  576, 1);
        convq5_k<128,128,2,4,2><<< 32, 512, 0, stream>>>(C3, Wp3, bb[3], 6,  9,  576, 1);
        CQ F4 = {f3p, ffm, 34, 147968, 10,  5,   32,  262144, 0};
        CQ C4 = {c3p, cfm, 10,  12800,  6,  3,    8,   16384, 0};
        convq5_k<256,256,2,4,1><<<256, 512, 0, stream>>>(F4, Wp4, bb[4], 7, 18, 1152, 0);
        convq5_k<256,128,2,4,1><<< 32, 512, 0, stream>>>(C4, Wp4, bb[4], 7, 18, 1152, 0);
    }

    // ---- xcorr (MFMA) + fused band-reduce + BN ----
    xcmf_k<<<400, 256, 0, stream>>>(ffm, cfm, Rbuf);
    bn_k<<<1, 1024, 0, stream>>>(Rbuf, part, gamma, beta, out);
}

// Round 19
// 209.567 us; speedup vs baseline: 1.1411x; 1.1411x over previous
//
#include <hip/hip_runtime.h>

// ---------------------------------------------------------------------------
// CorrelationalDetector R19: recover R15 optimum + split BN.
//  - L3/L4 reverted to R15's convq3_k (128x128, 2 blk/CU, K-half counted
//    vmcnt, merged frame+crop grids 544/1088 -- proven 66.2us L4 incl crop;
//    R13/R18/merge arithmetic shows any 256^2+separate-crop combo >= this).
//  - bn split: xst_k (157 blocks, band-reduce + atomic sum/sumsq) + bn2_k
//    (elementwise). Old bn was 1 block streaming 1.3MB strided (~12us).
//    stats slots zeroed in prep_k.
//  Everything else identical to R18/R15.
// ---------------------------------------------------------------------------

typedef __bf16 bf16x8 __attribute__((ext_vector_type(8)));
typedef float f32x4 __attribute__((ext_vector_type(4)));
typedef unsigned int u32x4 __attribute__((ext_vector_type(4)));
typedef unsigned int u32x2 __attribute__((ext_vector_type(2)));
typedef unsigned short u16;

#define AS1 __attribute__((address_space(1)))
#define AS3 __attribute__((address_space(3)))

__device__ __forceinline__ u16 f2bf(float v) {
    unsigned u = __float_as_uint(v);
    u += 0x7fffu + ((u >> 16) & 1u);          // RNE
    return (u16)(u >> 16);
}

__device__ __forceinline__ bf16x8 ldb8(const u16* p) {
    return *(const bf16x8*)p;
}

__device__ __forceinline__ bf16x8 zerob8() {
    u32x4 z = {0u, 0u, 0u, 0u};
    bf16x8 r;
    __builtin_memcpy(&r, &z, 16);
    return r;
}

__device__ __forceinline__ void gload16(const u16* g, u16* l) {
    __builtin_amdgcn_global_load_lds((const AS1 void*)g, (AS3 void*)l, 16, 0, 0);
}

template<int N> __device__ __forceinline__ void wait_vm() {
    asm volatile("s_waitcnt vmcnt(%0)" :: "i"(N) : "memory");
}

__device__ __forceinline__ void bar_mem() {
    asm volatile("" ::: "memory");
    __builtin_amdgcn_s_barrier();
    asm volatile("" ::: "memory");
}

// XCD-bijective logical block id (requires gridDim.x % 8 == 0)
__device__ __forceinline__ int xcd_logical() {
    const int nb = (int)gridDim.x;
    return ((int)blockIdx.x & 7) * (nb >> 3) + ((int)blockIdx.x >> 3);
}

// per-side geometry
struct CP { const u16* in; u16* out; int IWp, inSS, OWsh, OWpo, outSS, npt; };
struct CQ { const u16* in; u16* out; int IWp, inSS, HWsh, OWsh, OWpo, outSS, pad_o; };

// ---- merged prep: weight pack (blocks [0,1484)) + halo zero (rest) ---------
struct HZd { unsigned long long ptr; int B, Hp, Wpx, w8, cum; };
struct HZall { HZd d[8]; int total; };

__device__ __forceinline__ void packone(const float* W, u16* Wp, int idx,
                                        int ICsh, int Kpad)
{
    const int k = idx % Kpad, oc = idx / Kpad;
    const int tap = k >> ICsh, ic = k & ((1 << ICsh) - 1);
    const float v = (tap < 9) ? W[((size_t)(oc << ICsh) + ic) * 9 + tap] : 0.f;
    Wp[idx] = f2bf(v);
}

__global__ __launch_bounds__(256)
void prep_k(HZall h,
            const float* __restrict__ W1, const float* __restrict__ W2,
            const float* __restrict__ W3, const float* __restrict__ W4,
            u16* __restrict__ Wc1, u16* __restrict__ Wp2,
            u16* __restrict__ Wp3, u16* __restrict__ Wp4,
            float* __restrict__ stats)
{
    if (blockIdx.x == 1484 && threadIdx.x < 2) stats[threadIdx.x] = 0.f;
    if (blockIdx.x < 1484) {
        const int i = blockIdx.x * 256 + threadIdx.x;
        if (i < 1024) {                       // Wc1: [16][64], k = ky*16+kx*4+ic
            const int k = i & 63, oc = i >> 6;
            const int ky = k >> 4, kx = (k >> 2) & 3, ic = k & 3;
            const float v = (ky < 3 && kx < 3 && ic < 3) ? W1[oc * 27 + ic * 9 + ky * 3 + kx] : 0.f;
            Wc1[i] = f2bf(v);
        } else if (i < 11264) {
            packone(W2, Wp2, i - 1024, 4, 160);
        } else if (i < 84992) {
            packone(W3, Wp3, i - 11264, 6, 576);
        } else if (i < 379904) {
            packone(W4, Wp4, i - 84992, 7, 1152);
        }
        return;
    }
    const int nblk = gridDim.x - 1484;
    for (int i = (blockIdx.x - 1484) * 256 + threadIdx.x; i < h.total; i += nblk * 256) {
        int di = 0;
        #pragma unroll
        for (int j = 1; j < 8; ++j) if (i >= h.d[j].cum) di = j;
        const HZd D = h.d[di];
        const int loc = i - D.cum;
        const int w = loc % D.w8; int t2 = loc / D.w8;
        const int bord = 2 * D.Wpx + 2 * (D.Hp - 2);
        const int pb = t2 % bord; const int b = t2 / bord;
        int oh, ow;
        if (pb < D.Wpx)            { oh = 0;        ow = pb; }
        else if (pb < 2 * D.Wpx)   { oh = D.Hp - 1; ow = pb - D.Wpx; }
        else { const int q = pb - 2 * D.Wpx; oh = 1 + (q >> 1); ow = (q & 1) ? (D.Wpx - 1) : 0; }
        ((unsigned long long*)D.ptr)[((size_t)b * D.Hp * D.Wpx + (size_t)oh * D.Wpx + ow) * D.w8 + w] = 0ull;
    }
}

// ---- L0 body ----------------------------------------------------------------
__device__ __forceinline__ void conv0_body(const float* __restrict__ in,
                                           const float* __restrict__ W,
                                           const float* __restrict__ bias,
                                           u16* __restrict__ outP,
                                           int IH, int IW, int OH, int OW, int idx)
{
    const int OW4 = OW >> 2;
    const int OWp = OW + 2, OHp = OH + 2;
    const int ow4 = idx % OW4; int t = idx / OW4;
    const int oh = t % OH;  const int b = t / OH;
    const int owb = ow4 * 4;
    float a0[4], a1[4], a2[4];
    #pragma unroll
    for (int j = 0; j < 4; ++j) { a0[j] = bias[0]; a1[j] = bias[1]; a2[j] = bias[2]; }
    const float* inb = in + (size_t)b * 3 * IH * IW;
    const int xbase = owb * 2 - 1;
    #pragma unroll
    for (int ic = 0; ic < 3; ++ic) {
        const float* ip = inb + (size_t)ic * IH * IW;
        #pragma unroll
        for (int ky = 0; ky < 3; ++ky) {
            const int y = oh * 2 - 1 + ky;
            if ((unsigned)y >= (unsigned)IH) continue;
            const float* rp = ip + (size_t)y * IW;
            float xr[9];
            #pragma unroll
            for (int i2 = 0; i2 < 9; ++i2) {
                const int x = xbase + i2;
                xr[i2] = ((unsigned)x < (unsigned)IW) ? rp[x] : 0.f;
            }
            #pragma unroll
            for (int kx = 0; kx < 3; ++kx) {
                const float w0 = W[0 * 27 + ic * 9 + ky * 3 + kx];
                const float w1 = W[1 * 27 + ic * 9 + ky * 3 + kx];
                const float w2 = W[2 * 27 + ic * 9 + ky * 3 + kx];
                #pragma unroll
                for (int j = 0; j < 4; ++j) {
                    const float xv = xr[2 * j + kx];
                    a0[j] += xv * w0; a1[j] += xv * w1; a2[j] += xv * w2;
                }
            }
        }
    }
    u16* op = outP + (((size_t)b * OHp + oh + 1) * OWp + owb + 1) * 4;
    #pragma unroll
    for (int j = 0; j < 4; ++j) {
        u32x2 pk;
        pk[0] = (unsigned)f2bf(fmaxf(a0[j], 0.f)) | ((unsigned)f2bf(fmaxf(a1[j], 0.f)) << 16);
        pk[1] = (unsigned)f2bf(fmaxf(a2[j], 0.f));
        *(u32x2*)(op + j * 4) = pk;
    }
}

__global__ __launch_bounds__(256)
void conv0m_k(const float* __restrict__ crop, const float* __restrict__ frame,
              const float* __restrict__ W, const float* __restrict__ bias,
              u16* __restrict__ c0b, u16* __restrict__ f0b)
{
    if (blockIdx.x < 64)
        conv0_body(crop, W, bias, c0b, 64, 64, 32, 32, blockIdx.x * 256 + threadIdx.x);
    else
        conv0_body(frame, W, bias, f0b, 256, 256, 128, 128, (blockIdx.x - 64) * 256 + threadIdx.x);
}

// ---- L1 body: MFMA GEMM M=16 oc, K=64 --------------------------------------
__device__ __forceinline__ void conv1g_body(const u16* __restrict__ inP,
                                            const u16* __restrict__ Wc1,
                                            const float* __restrict__ bias,
                                            u16* __restrict__ outP,
                                            int IWp, int inSS, int OWp, int outSS,
                                            int OWsh, int HWsh, int w, int lane)
{
    const int lr = lane & 15, lg = lane >> 4;
    const int pxb = w * 64;
    const int OW = 1 << OWsh;

    const bf16x8 av0 = ldb8(Wc1 + lr * 64 + lg * 8);
    const bf16x8 av1 = ldb8(Wc1 + lr * 64 + 32 + lg * 8);
    const int ky0 = lg >> 1, kxb = (lg & 1) * 2;
    const int ky1 = 2 + (lg >> 1);

    f32x4 acc[4] = {};
    #pragma unroll
    for (int n = 0; n < 4; ++n) {
        const int px = pxb + n * 16 + lr;
        const int b = px >> HWsh;
        const int rem = px & ((1 << HWsh) - 1);
        const int oh = rem >> OWsh, ow = rem & (OW - 1);
        const u16* ib = inP + (size_t)b * inSS + (((size_t)(oh * 2)) * IWp + ow * 2) * 4;
        const bf16x8 bv0 = ldb8(ib + ((size_t)ky0 * IWp + kxb) * 4);
        acc[n] = __builtin_amdgcn_mfma_f32_16x16x32_bf16(av0, bv0, acc[n], 0, 0, 0);
        const bf16x8 bv1 = ldb8(ib + ((size_t)ky1 * IWp + kxb) * 4);
        acc[n] = __builtin_amdgcn_mfma_f32_16x16x32_bf16(av1, bv1, acc[n], 0, 0, 0);
    }

    const float b0 = bias[lg * 4], b1 = bias[lg * 4 + 1],
                b2 = bias[lg * 4 + 2], b3 = bias[lg * 4 + 3];
    #pragma unroll
    for (int n = 0; n < 4; ++n) {
        const int px = pxb + n * 16 + lr;
        const int b = px >> HWsh;
        const int rem = px & ((1 << HWsh) - 1);
        const int oh = rem >> OWsh, ow = rem & (OW - 1);
        const f32x4 a = acc[n];
        u32x2 pk;
        pk[0] = (unsigned)f2bf(fmaxf(a[0] + b0, 0.f)) | ((unsigned)f2bf(fmaxf(a[1] + b1, 0.f)) << 16);
        pk[1] = (unsigned)f2bf(fmaxf(a[2] + b2, 0.f)) | ((unsigned)f2bf(fmaxf(a[3] + b3, 0.f)) << 16);
        u16* op = outP + (size_t)b * outSS + (((size_t)(oh + 1)) * OWp + (ow + 1)) * 16 + lg * 4;
        *(u32x2*)op = pk;
    }
}

__global__ __launch_bounds__(256)
void conv1m_k(const u16* __restrict__ c0b, u16* __restrict__ c1p,
              const u16* __restrict__ f0b, u16* __restrict__ f1p,
              const u16* __restrict__ Wc1, const float* __restrict__ bias)
{
    const int wv = threadIdx.x >> 6, lane = threadIdx.x & 63;
    if (blockIdx.x < 64)
        conv1g_body(c0b, Wc1, bias, c1p, 34, 4624, 18, 5184, 4, 8, blockIdx.x * 4 + wv, lane);
    else
        conv1g_body(f0b, Wc1, bias, f1p, 130, 67600, 66, 69696, 6, 12, (blockIdx.x - 64) * 4 + wv, lane);
}

// ---- convq3 (R15): 128x128 K-half counted-vmcnt conv GEMM, 2 blk/CU --------
template<int BM, int BN, int NWM, int NWN, int S>
__global__ __launch_bounds__(512, 4)
void convq3_k(CQ F, CQ C, int splitPt, int nmt_sh,
              const u16* __restrict__ Wp, const float* __restrict__ bias,
              int IC_sh, int nt, int Kpad, int relu, int OCt)
{
    constexpr int MF = BM / (NWM * 16);
    constexpr int NF = BN / (NWN * 16);
    constexpr int AH = BM * 4 / 512;
    constexpr int BH = BN * 4 / 512;
    constexpr int WAIT  = 2 * AH + BH;
    constexpr int TAIL0 = AH + BH;
    constexpr int ASZ = 2 * 2 * BM * 4 * 8;
    constexpr int BSZ = 2 * 2 * BN * 4 * 8;

    __shared__ __align__(16) u16 SM[ASZ + BSZ];
    u16* Ab = SM;
    u16* Bb = SM + ASZ;

    const int lbid = xcd_logical();
    const int mt  = lbid & ((1 << nmt_sh) - 1);
    const int ptg = lbid >> nmt_sh;
    CQ P; int pt;
    if (ptg < splitPt) { P = F; pt = ptg; }
    else               { P = C; pt = ptg - splitPt; }
    const int ocb = mt * BM;

    const int t    = threadIdx.x;
    const int lane = t & 63;
    const int lr   = lane & 15, lg = lane >> 4;
    const int wv   = t >> 6;
    const int wm   = wv / NWN, wn = wv % NWN;

    const int IC = 1 << IC_sh;
    const int OW = 1 << P.OWsh;
    const int HWm = (1 << P.HWsh) - 1;
    const int pxb = pt * BN;

    const u16* apg[2 * AH];
    #pragma unroll
    for (int h = 0; h < 2; ++h)
        #pragma unroll
        for (int i = 0; i < AH; ++i) {
            const int j = i * 512 + t;
            const int row = j >> 2, o = j & 3;
            const int oct = h * 4 + (o ^ ((row ^ (row >> 2)) & 3));
            apg[h * AH + i] = Wp + (size_t)(ocb + row) * Kpad + oct * 8;
        }
    const u16* bpg[2 * BH];
    #pragma unroll
    for (int h = 0; h < 2; ++h)
        #pragma unroll
        for (int i = 0; i < BH; ++i) {
            const int j = i * 512 + t;
            const int row = j >> 2, o = j & 3;
            const int oct = h * 4 + (o ^ ((row ^ (row >> 2)) & 3));
            const int px = pxb + row;
            const int b = px >> P.HWsh;
            const int rem = px & HWm;
            const int oh = rem >> P.OWsh, ow = rem & (OW - 1);
            bpg[h * BH + i] = P.in + (size_t)b * P.inSS
                            + ((size_t)(oh * S) * P.IWp + ow * S) * IC + oct * 8;
        }

    f32x4 acc[MF][NF] = {};

    auto STAGE_A = [&](int buf, int h, int kb) {
        u16* dst = Ab + (size_t)((buf * 2 + h) * BM * 4) * 8;
        #pragma unroll
        for (int i = 0; i < AH; ++i)
            gload16(apg[h * AH + i] + kb, dst + (size_t)(i * 512 + t) * 8);
    };
    auto STAGE_B = [&](int buf, int h, int kb) {
        const int tap = kb >> IC_sh;          // uniform: BK=64 <= IC
        const int ky = (tap * 11) >> 5, kx = tap - 3 * ky;
        const size_t off = ((size_t)(ky * P.IWp + kx) << IC_sh) + (kb & (IC - 1));
        u16* dst = Bb + (size_t)((buf * 2 + h) * BN * 4) * 8;
        #pragma unroll
        for (int i = 0; i < BH; ++i)
            gload16(bpg[h * BH + i] + off, dst + (size_t)(i * 512 + t) * 8);
    };

    STAGE_A(0, 0, 0); STAGE_B(0, 0, 0); STAGE_A(0, 1, 0); STAGE_B(0, 1, 0);

    for (int ks = 0; ks < nt; ++ks) {
        const int cur = ks & 1, nxt = cur ^ 1;
        const int kb1 = (ks + 1) * 64;
        const bool pf = (ks + 1 < nt);
        bf16x8 af[MF], bf_[NF];

        #pragma unroll
        for (int kk = 0; kk < 2; ++kk) {
            if (pf) STAGE_A(nxt, kk, kb1);
            if (pf)            wait_vm<WAIT>();
            else if (kk == 0)  wait_vm<TAIL0>();
            else               wait_vm<0>();
            bar_mem();

            const u16* Abase = Ab + (size_t)((cur * 2 + kk) * BM * 4) * 8;
            const u16* Bbase = Bb + (size_t)((cur * 2 + kk) * BN * 4) * 8;
            #pragma unroll
            for (int n = 0; n < NF; ++n) {
                const int row = wn * (NF * 16) + n * 16 + lr;
                const int o = lg ^ ((row ^ (row >> 2)) & 3);
                bf_[n] = ldb8(Bbase + (size_t)(row * 4 + o) * 8);
            }
            #pragma unroll
            for (int m = 0; m < MF; ++m) {
                const int row = wm * (MF * 16) + m * 16 + lr;
                const int o = lg ^ ((row ^ (row >> 2)) & 3);
                af[m] = ldb8(Abase + (size_t)(row * 4 + o) * 8);
            }
            if (pf) STAGE_B(nxt, kk, kb1);

            __builtin_amdgcn_s_setprio(1);
            #pragma unroll
            for (int m = 0; m < MF; ++m)
                #pragma unroll
                for (int n = 0; n < NF; ++n)
                    acc[m][n] = __builtin_amdgcn_mfma_f32_16x16x32_bf16(af[m], bf_[n], acc[m][n], 0, 0, 0);
            __builtin_amdgcn_s_setprio(0);
        }
    }

    // ---- coalesced epilogue via LDS C-tile (BN x BM bf16 = 32KB) ----
    bar_mem();
    unsigned long long* SM64 = (unsigned long long*)SM;
    #pragma unroll
    for (int m = 0; m < MF; ++m) {
        const int ocl = wm * (MF * 16) + m * 16 + lg * 4;
        const float b0 = bias[ocb + ocl], b1 = bias[ocb + ocl + 1],
                    b2 = bias[ocb + ocl + 2], b3 = bias[ocb + ocl + 3];
        #pragma unroll
        for (int n = 0; n < NF; ++n) {
            const int px = wn * (NF * 16) + n * 16 + lr;
            const f32x4 a = acc[m][n];
            float v0 = a[0] + b0, v1 = a[1] + b1, v2 = a[2] + b2, v3 = a[3] + b3;
            if (relu) {
                v0 = fmaxf(v0, 0.f); v1 = fmaxf(v1, 0.f);
                v2 = fmaxf(v2, 0.f); v3 = fmaxf(v3, 0.f);
            }
            u32x2 pk;
            pk[0] = (unsigned)f2bf(v0) | ((unsigned)f2bf(v1) << 16);
            pk[1] = (unsigned)f2bf(v2) | ((unsigned)f2bf(v3) << 16);
            const int sw = ((px & 3) << 1) | ((px >> 2) & 1);
            const int u8 = (ocl >> 2) ^ (sw << 1);
            *(u32x2*)&SM64[(size_t)px * (BM / 4) + u8] = pk;
        }
    }
    bar_mem();
    constexpr int UPX16 = BM / 8;
    constexpr int NIT = BN * UPX16 / 512;
    #pragma unroll
    for (int it = 0; it < NIT; ++it) {
        const int g = it * 512 + t;
        const int px = g / UPX16;
        const int ul = g & (UPX16 - 1);
        const int sw2 = ((px & 3) << 1) | ((px >> 2) & 1);
        const int phys = ul ^ sw2;
        const u32x4 val = *(const u32x4*)&SM[((size_t)px * UPX16 + phys) * 8];
        const int flat = pxb + px;
        const int b = flat >> P.HWsh;
        const int rem = flat & HWm;
        const int oh = rem >> P.OWsh, ow = rem & (OW - 1);
        u16* dst = P.out + (size_t)b * P.outSS
                 + (((size_t)(oh + P.pad_o)) * P.OWpo + (ow + P.pad_o)) * OCt
                 + ocb + ul * 8;
        *(u32x4*)dst = val;
    }
}

// ---- convg4: L2 conv, 4-buffer 3-deep pipeline with COALESCED staging ------
template<int BM, int BN, int NWM, int NWN, int S>
__global__ __launch_bounds__(256, 2)
void convg4_k(CP A, CP B, int split,
              const u16* __restrict__ Wp, const float* __restrict__ bias,
              int IC_sh, int pad_o, int Kreal, int nt, int Kpad, int relu, int OCtot)
{
    constexpr int MF = BM / (NWM * 16);
    constexpr int NF = BN / (NWN * 16);
    constexpr int ASLOT = BM * 4;
    constexpr int BSLOT = BN * 4;
    constexpr int AISS = ASLOT / 256;
    constexpr int BISS = BSLOT / 256;
    constexpr int NSTG = AISS + BISS;

    __shared__ __align__(16) u16 Ab[4][ASLOT * 8];
    __shared__ __align__(16) u16 Bb[4][BSLOT * 8];

    const int lbid = xcd_logical();
    CP P; int bid;
    if (lbid < split) { P = A; bid = lbid; }
    else              { P = B; bid = lbid - split; }

    const int t    = threadIdx.x;
    const int wv   = t >> 6, lane = t & 63;
    const int lr   = lane & 15, lg = lane >> 4;
    const int wm   = wv / NWN, wn = wv % NWN;

    const int tilesPerB = (OCtot / BM) * P.npt;
    const int b  = bid / tilesPerB;
    const int r0 = bid - b * tilesPerB;
    const int mt = r0 / P.npt, pt = r0 - mt * P.npt;
    const int ocb = mt * BM, pxb = pt * BN;
    const int IC = 1 << IC_sh;
    const int OW = 1 << P.OWsh;

    const u16* __restrict__ inb = P.in + (size_t)b * P.inSS;

    const u16* agp[AISS];
    #pragma unroll
    for (int i = 0; i < AISS; ++i) {
        const int j = i * 256 + t;
        const int row = j >> 2, c = j & 3;
        const int og = c ^ ((row ^ (row >> 2)) & 3);
        agp[i] = Wp + (size_t)(ocb + row) * Kpad + og * 8;
    }
    const u16* bpx[BISS]; int bog8[BISS];
    #pragma unroll
    for (int i = 0; i < BISS; ++i) {
        const int j = i * 256 + t;
        const int row = j >> 2, c = j & 3;
        const int og = c ^ ((row ^ (row >> 2)) & 3);
        const int px = pxb + row;
        const int oh = px >> P.OWsh, ow = px & (OW - 1);
        bpx[i] = inb + ((size_t)(oh * S) * P.IWp + ow * S) * IC;
        bog8[i] = og * 8;
    }

    f32x4 acc[MF][NF] = {};

    auto STAGE = [&](int buf, int kb) {
        #pragma unroll
        for (int i = 0; i < AISS; ++i)
            gload16(agp[i] + kb, &Ab[buf][(size_t)(i * 256 + t) * 8]);
        #pragma unroll
        for (int i = 0; i < BISS; ++i) {
            const int k = kb + bog8[i];
            const int tap = k >> IC_sh;
            const int ic = k & (IC - 1);
            const int ky = (tap * 11) >> 5, kx = tap - 3 * ky;
            const u16* g = bpx[i] + ((size_t)ky * P.IWp + kx) * IC + ic;
            if (k >= Kreal) g = inb;           // A is zero there; any valid addr
            gload16(g, &Bb[buf][(size_t)(i * 256 + t) * 8]);
        }
    };

    STAGE(0, 0);
    if (1 < nt) STAGE(1, 32);
    if (2 < nt) STAGE(2, 64);

    for (int ks = 0; ks < nt; ++ks) {
        const int rem = nt - 1 - ks;
        if (rem >= 2)      wait_vm<2 * NSTG>();
        else if (rem == 1) wait_vm<NSTG>();
        else               wait_vm<0>();
        bar_mem();
        if (ks + 3 < nt) STAGE((ks + 3) & 3, (ks + 3) * 32);

        const int cur = ks & 3;
        bf16x8 af[MF], bf_[NF];
        #pragma unroll
        for (int m = 0; m < MF; ++m) {
            const int row = wm * (MF * 16) + m * 16 + lr;
            const int o = lg ^ ((row ^ (row >> 2)) & 3);
            af[m] = ldb8(&Ab[cur][(size_t)(row * 4 + o) * 8]);
        }
        #pragma unroll
        for (int n = 0; n < NF; ++n) {
            const int row = wn * (NF * 16) + n * 16 + lr;
            const int o = lg ^ ((row ^ (row >> 2)) & 3);
            bf_[n] = ldb8(&Bb[cur][(size_t)(row * 4 + o) * 8]);
        }

        __builtin_amdgcn_s_setprio(1);
        #pragma unroll
        for (int m = 0; m < MF; ++m)
            #pragma unroll
            for (int n = 0; n < NF; ++n)
                acc[m][n] = __builtin_amdgcn_mfma_f32_16x16x32_bf16(af[m], bf_[n], acc[m][n], 0, 0, 0);
        __builtin_amdgcn_s_setprio(0);
    }

    #pragma unroll
    for (int m = 0; m < MF; ++m) {
        const int oc0 = ocb + wm * (MF * 16) + m * 16 + lg * 4;
        const float b0 = bias[oc0], b1 = bias[oc0 + 1], b2 = bias[oc0 + 2], b3 = bias[oc0 + 3];
        #pragma unroll
        for (int n = 0; n < NF; ++n) {
            const int px = pxb + wn * (NF * 16) + n * 16 + lr;
            const int oh = px >> P.OWsh, ow = px & (OW - 1);
            const f32x4 a = acc[m][n];
            float v0 = a[0] + b0, v1 = a[1] + b1, v2 = a[2] + b2, v3 = a[3] + b3;
            if (relu) {
                v0 = fmaxf(v0, 0.f); v1 = fmaxf(v1, 0.f);
                v2 = fmaxf(v2, 0.f); v3 = fmaxf(v3, 0.f);
            }
            u32x2 pk;
            pk[0] = (unsigned)f2bf(v0) | ((unsigned)f2bf(v1) << 16);
            pk[1] = (unsigned)f2bf(v2) | ((unsigned)f2bf(v3) << 16);
            u16* op = P.out + (size_t)b * P.outSS +
                      (((size_t)(oh + pad_o)) * P.OWpo + (ow + pad_o)) * (size_t)OCtot + oc0;
            *(u32x2*)op = pk;
        }
    }
}

// ---- xcorr as batched MFMA GEMM --------------------------------------------
__global__ __launch_bounds__(256)
void xcmf_k(const u16* __restrict__ ffm, const u16* __restrict__ cfm,
            float* __restrict__ R)
{
    const int w    = blockIdx.x * 4 + (threadIdx.x >> 6);   // 1600 waves
    const int lane = threadIdx.x & 63;
    const int lr   = lane & 15, lg = lane >> 4;
    const int b  = w / 25;
    const int tp = w - b * 25;

    const int col0 = tp * 32 + lr;
    const int col1 = col0 + 16;
    const int y0 = col0 / 25, x0 = col0 - y0 * 25;
    const int y1 = col1 / 25, x1 = col1 - y1 * 25;

    const u16* fb = ffm + (size_t)b * 262144;
    const u16* f0 = fb + ((size_t)y0 * 32 + x0) * 256 + lg * 8;
    const u16* f1 = fb + ((size_t)y1 * 32 + x1) * 256 + lg * 8;
    const u16* ab = cfm + (size_t)b * 16384 + (size_t)lr * 2048 + lg * 8;
    const bool arow = (lr < 8);

    f32x4 acc0 = {}, acc1 = {};
    #pragma unroll 4
    for (int kb = 0; kb < 2048; kb += 32) {
        const bf16x8 av = arow ? ldb8(ab + kb) : zerob8();
        const bf16x8 bv0 = ldb8(f0 + kb);
        const bf16x8 bv1 = ldb8(f1 + kb);
        acc0 = __builtin_amdgcn_mfma_f32_16x16x32_bf16(av, bv0, acc0, 0, 0, 0);
        acc1 = __builtin_amdgcn_mfma_f32_16x16x32_bf16(av, bv1, acc1, 0, 0, 0);
    }

    if (lg < 2) {
        float* rb = R + (size_t)b * 6400;
        #pragma unroll
        for (int j = 0; j < 4; ++j) {
            const int d = lg * 4 + j;
            rb[(size_t)d * 800 + col0] = acc0[j];
            rb[(size_t)d * 800 + col1] = acc1[j];
        }
    }
}

// ---- band-reduce + global stats (multi-block, atomics) ---------------------
__global__ __launch_bounds__(256)
void xst_k(const float* __restrict__ R, float* __restrict__ part,
           float* __restrict__ stats)
{
    const int i = blockIdx.x * 256 + threadIdx.x;
    float v = 0.f;
    if (i < 40000) {
        const int b = i / 625;
        const int o = i - b * 625;
        const float* rb = R + (size_t)b * 6400 + o;
        #pragma unroll
        for (int d = 0; d < 8; ++d) v += rb[(size_t)d * 800 + d * 25];
        part[i] = v;
    }
    __shared__ float rs[256], rq[256];
    const int tid = threadIdx.x;
    rs[tid] = (i < 40000) ? v : 0.f;
    rq[tid] = (i < 40000) ? v * v : 0.f;
    __syncthreads();
    for (int off = 128; off > 0; off >>= 1) {
        if (tid < off) { rs[tid] += rs[tid + off]; rq[tid] += rq[tid + off]; }
        __syncthreads();
    }
    if (tid == 0) {
        atomicAdd(&stats[0], rs[0]);
        atomicAdd(&stats[1], rq[0]);
    }
}

// ---- BN finalize (elementwise) ---------------------------------------------
__global__ __launch_bounds__(256)
void bn2_k(const float* __restrict__ part, const float* __restrict__ stats,
           const float* __restrict__ gamma, const float* __restrict__ beta,
           float* __restrict__ out)
{
    const int i = blockIdx.x * 256 + threadIdx.x;
    if (i >= 40000) return;
    const float m = stats[0] * (1.f / 40000.f);
    const float var = stats[1] * (1.f / 40000.f) - m * m;
    out[i] = (part[i] - m) * rsqrtf(var + 1e-5f) * gamma[0] + beta[0];
}

// ---------------------------------------------------------------------------

extern "C" void kernel_launch(void* const* d_in, const int* in_sizes, int n_in,
                              void* d_out, int out_size, void* d_ws, size_t ws_size,
                              hipStream_t stream)
{
    (void)in_sizes; (void)n_in; (void)out_size; (void)ws_size;
    const float* crop  = (const float*)d_in[0];
    const float* frame = (const float*)d_in[1];
    const float* W[5]; const float* bb[5];
    for (int i = 0; i < 5; ++i) { W[i] = (const float*)d_in[2 + 2*i]; bb[i] = (const float*)d_in[3 + 2*i]; }
    const float* gamma = (const float*)d_in[12];
    const float* beta  = (const float*)d_in[13];
    float* out = (float*)d_out;

    unsigned char* ws = (unsigned char*)d_ws;
    u16*   f0b  = (u16*)(ws + 0);             // [64][130][130][4]   8,652,800 B (dead after fL1)
    u16*   f1p  = (u16*)(ws + 8652800);       // [64][66][66][16]    8,921,088 B (dead after fL2)
    u16*   f2p  = (u16*)(ws + 17573888);      // [64][66][66][64]   35,684,352 B (dead after fL3)
    u16*   f3p  = (u16*)(ws + 53258240);      // [64][34][34][128]  18,939,904 B
    u16*   ffm  = (u16*)(ws + 0);             // [64][32][32][256]  33,554,432 B (aliases dead f0b..f2p)
    u16*   c0b  = (u16*)(ws + 72198144);      // [64][34][34][4]       591,872 B
    u16*   c1p  = (u16*)(ws + 72790016);      // [64][18][18][16]      663,552 B
    u16*   c2p  = (u16*)(ws + 73453568);      // [64][18][18][64]    2,654,208 B
    u16*   c3p  = (u16*)(ws + 76107776);      // [64][10][10][128]   1,638,400 B
    u16*   cfm  = (u16*)(ws + 77746176);      // [64][8][8][256]     2,097,152 B
    u16*   Wc1  = (u16*)(ws + 79843328);      // [16][64]
    u16*   Wp2  = (u16*)(ws + 79845376);      // [64][160]
    u16*   Wp3  = (u16*)(ws + 79865856);      // [128][576]
    u16*   Wp4  = (u16*)(ws + 80013312);      // [256][1152]
    float* Rbuf = (float*)(ws + 80603136);    // [64][8][800] f32
    float* part = (float*)(ws + 82241536);    // [40000] f32
    float* stats= (float*)(ws + 82401536);    // [2] f32 (sum, sumsq)

    // ---- merged prep (weight pack + halo zero + stats zero), one launch ----
    HZall hz;
    const unsigned long long ptrs[8] = {(unsigned long long)c0b, (unsigned long long)c1p,
        (unsigned long long)c2p, (unsigned long long)c3p, (unsigned long long)f0b,
        (unsigned long long)f1p, (unsigned long long)f2p, (unsigned long long)f3p};
    const int Hps[8] = {34, 18, 18, 10, 130, 66, 66, 34};
    const int w8s[8] = {1, 4, 16, 32, 1, 4, 16, 32};
    int cum = 0;
    for (int i = 0; i < 8; ++i) {
        hz.d[i].ptr = ptrs[i]; hz.d[i].B = 64; hz.d[i].Hp = Hps[i];
        hz.d[i].Wpx = Hps[i]; hz.d[i].w8 = w8s[i]; hz.d[i].cum = cum;
        cum += 64 * (2 * Hps[i] + 2 * (Hps[i] - 2)) * w8s[i];
    }
    hz.total = cum;
    prep_k<<<1856, 256, 0, stream>>>(hz, W[1], W[2], W[3], W[4], Wc1, Wp2, Wp3, Wp4, stats);

    // ---- merged heads (crop+frame): L0, L1, L2 ----
    conv0m_k<<<1088, 256, 0, stream>>>(crop, frame, W[0], bb[0], c0b, f0b);
    conv1m_k<<<1088, 256, 0, stream>>>(c0b, c1p, f0b, f1p, Wc1, bb[1]);
    {
        CP Ac = {c1p, c2p, 18,  5184, 4, 18, 20736,  1};
        CP Bf = {f1p, f2p, 66, 69696, 6, 66, 278784, 16};
        convg4_k<64,256,1,4,1><<<1088, 256, 0, stream>>>(Ac, Bf, 64, Wp2, bb[2],
            4, 1, 144, 5, 160, 1, 64);
    }

    // ---- L3 (frame+crop merged), L4 (frame+crop merged), 128x128 tiles ----
    {
        //        in   out  IWp inSS    HWsh OWsh OWpo outSS  pad
        CQ F3 = {f2p, f3p, 66, 278784, 10,  5,   34,  147968, 1};
        CQ C3 = {c2p, c3p, 18,  20736,  6,  3,   10,   12800, 1};
        convq3_k<128,128,2,4,2><<< 544, 512, 0, stream>>>(F3, C3, 512, 0, Wp3, bb[3], 6,  9,  576, 1, 128);
        CQ F4 = {f3p, ffm, 34, 147968, 10,  5,   32,  262144, 0};
        CQ C4 = {c3p, cfm, 10,  12800,  6,  3,    8,   16384, 0};
        convq3_k<128,128,2,4,1><<<1088, 512, 0, stream>>>(F4, C4, 512, 1, Wp4, bb[4], 7, 18, 1152, 0, 256);
    }

    // ---- xcorr (MFMA) + band-reduce/stats + BN finalize ----
    xcmf_k<<<400, 256, 0, stream>>>(ffm, cfm, Rbuf);
    xst_k<<<157, 256, 0, stream>>>(Rbuf, part, stats);
    bn2_k<<<157, 256, 0, stream>>>(part, stats, gamma, beta, out);
}